// Round 7
// baseline (397.442 us; speedup 1.0000x reference)
//
#include <hip/hip_runtime.h>

#define N_NODES 100000
#define N_EDGES 1600000
#define NPB 32                       // nodes per bucket (dst >> 5)
#define NB (N_NODES / NPB)           // 3125 buckets
#define SEG 8                        // segments per bucket (XCD-local append)
#define CAP_S 128                    // slots per segment (mean 64 + 8 sigma)

// ---------------- JAX threefry2x32 (partitionable scheme) ----------------
struct U2 { unsigned a, b; };

__host__ __device__ constexpr U2 tf2x32(unsigned k0, unsigned k1, unsigned c0, unsigned c1) {
  unsigned ks2 = k0 ^ k1 ^ 0x1BD11BDAu;
  unsigned x0 = c0 + k0, x1 = c1 + k1;
#define TFR(r) { x0 += x1; x1 = (x1 << (r)) | (x1 >> (32 - (r))); x1 ^= x0; }
  TFR(13) TFR(15) TFR(26) TFR(6)
  x0 += k1;  x1 += ks2 + 1u;
  TFR(17) TFR(29) TFR(16) TFR(24)
  x0 += ks2; x1 += k0 + 2u;
  TFR(13) TFR(15) TFR(26) TFR(6)
  x0 += k0;  x1 += k1 + 3u;
  TFR(17) TFR(29) TFR(16) TFR(24)
  x0 += k1;  x1 += ks2 + 4u;
  TFR(13) TFR(15) TFR(26) TFR(6)
  x0 += ks2; x1 += k0 + 5u;
#undef TFR
  return U2{x0, x1};
}

constexpr U2 DK0 = tf2x32(0u, 42u, 0u, 0u);
constexpr U2 DK1 = tf2x32(0u, 42u, 0u, 1u);

__device__ __forceinline__ bool keep_bit(unsigned k0, unsigned k1, unsigned j) {
  U2 w = tf2x32(k0, k1, 0u, j);
  return ((w.a ^ w.b) >> 31) == 0u;
}

// bf16 storage helpers (RNE pack, shift unpack)
__device__ __forceinline__ unsigned short f2bf(float f) {
  unsigned u = __float_as_uint(f);
  u += 0x7FFFu + ((u >> 16) & 1u);
  return (unsigned short)(u >> 16);
}
__device__ __forceinline__ float bf2f(unsigned short s) {
  return __uint_as_float((unsigned)s << 16);
}

// ------ Kernel A: xl = bf16(x@W1_l), xr = x@W1_r (wave per row) ----------
__global__ __launch_bounds__(256) void k_transform1(
    const float* __restrict__ x, const float* __restrict__ Wl,
    const float* __restrict__ Wr, unsigned short* __restrict__ xlb,
    float* __restrict__ xr) {
  int wid = (int)((blockIdx.x * blockDim.x + threadIdx.x) >> 6);
  int lane = threadIdx.x & 63;
  if (wid >= N_NODES) return;
  float xv = x[wid * 64 + lane];
  const float* W = (lane < 32) ? Wl : Wr;
  int c = lane & 31;
  float s = 0.f;
#pragma unroll
  for (int k = 0; k < 64; ++k) {
    float b = __shfl(xv, k, 64);
    s += b * W[k * 32 + c];
  }
  if (lane < 32) xlb[wid * 32 + c] = f2bf(s);
  else           xr[wid * 32 + c] = s;
}

// ---------------- Binning: 8 XCD-local segments per bucket ---------------
__global__ __launch_bounds__(256) void k_bin(
    const int* __restrict__ src, const int* __restrict__ dst,
    int* __restrict__ scur, unsigned* __restrict__ buf) {
  int e = (int)(blockIdx.x * blockDim.x + threadIdx.x);
  if (e >= N_EDGES) return;
  int d = dst[e];
  int cell = (d >> 5) * SEG + (blockIdx.x & (SEG - 1));
  unsigned packed = (unsigned)src[e] | ((unsigned)(d & 31) << 17);
  int p = atomicAdd(&scur[cell], 1);
  if (p < CAP_S) buf[(size_t)cell * CAP_S + p] = packed;
}

// --------- single-block exclusive scan of bucket totals -> bbase ----------
__global__ __launch_bounds__(1024) void k_bscan(
    const int* __restrict__ scur, int* __restrict__ bbase) {
  __shared__ int warp_sums[16];
  __shared__ int s_running;
  int t = threadIdx.x;
  int lane = t & 63, w = t >> 6;
  if (t == 0) s_running = 0;
  __syncthreads();
  for (int base = 0; base < NB; base += 1024) {
    int i = base + t;
    int v = 0;
    if (i < NB) {
#pragma unroll
      for (int g = 0; g < SEG; ++g) v += min(scur[i * SEG + g], CAP_S);
    }
    int x = v;
#pragma unroll
    for (int o = 1; o < 64; o <<= 1) {
      int y = __shfl_up(x, o, 64);
      if (lane >= o) x += y;
    }
    if (lane == 63) warp_sums[w] = x;
    __syncthreads();
    if (w == 0) {
      int ws = (lane < 16) ? warp_sums[lane] : 0;
#pragma unroll
      for (int o = 1; o < 16; o <<= 1) {
        int y = __shfl_up(ws, o, 64);
        if (lane >= o) ws += y;
      }
      if (lane < 16) warp_sums[lane] = ws;
    }
    __syncthreads();
    int incl = x + (w > 0 ? warp_sums[w - 1] : 0);
    int excl = s_running + incl - v;
    if (i < NB) bbase[i] = excl;
    __syncthreads();
    if (t == 1023) s_running += incl;
    __syncthreads();
  }
}

// ------ block per bucket: LDS degree count + prefix, coalesced CSR fill ---
__global__ __launch_bounds__(256) void k_bfill(
    const unsigned* __restrict__ buf, const int* __restrict__ scur,
    const int* __restrict__ bbase, int* __restrict__ deg,
    int* __restrict__ offs, int* __restrict__ eidx) {
  __shared__ int ncnt[NPB];
  __shared__ int ncur[NPB];
  __shared__ int segn[SEG];
  int b = blockIdx.x, t = threadIdx.x;
  if (t < NPB) ncnt[t] = 0;
  if (t < SEG) segn[t] = min(scur[b * SEG + t], CAP_S);
  __syncthreads();
  const unsigned* bb = buf + (size_t)b * SEG * CAP_S;
  for (int slot = t; slot < SEG * CAP_S; slot += 256) {
    int g = slot / CAP_S, j = slot % CAP_S;
    if (j < segn[g]) atomicAdd(&ncnt[bb[slot] >> 17], 1);
  }
  __syncthreads();
  if (t < 64) {                       // wave 0: 32-wide exclusive scan
    int lane = t;
    int c = (lane < NPB) ? ncnt[lane] : 0;
    int x = c;
#pragma unroll
    for (int o = 1; o < 32; o <<= 1) {
      int y = __shfl_up(x, o, 64);
      if (lane >= o) x += y;
    }
    if (lane < NPB) {
      int excl = x - c;
      ncur[lane] = excl;
      int gn = b * NPB + lane;
      deg[gn] = c;
      offs[gn] = bbase[b] + excl;
    }
  }
  __syncthreads();
  int base = bbase[b];
  for (int slot = t; slot < SEG * CAP_S; slot += 256) {
    int g = slot / CAP_S, j = slot % CAP_S;
    if (j < segn[g]) {
      unsigned w = bb[slot];
      int p = atomicAdd(&ncur[w >> 17], 1);
      eidx[base + p] = (int)(w & 0x1FFFF);
    }
  }
}

// ---- Gather layer 1: hp = bf16(dropout(lrelu(mean(xl[nbrs])+b1+xr))) ----
// One wave per node, half-wave per edge; broadcast index loads; 8 bf16
// rows (64B each) in flight per half-wave. shfl only after reconvergence.
__global__ __launch_bounds__(256) void k_gather1(
    const unsigned short* __restrict__ xlb, const float* __restrict__ xr,
    const int* __restrict__ offs, const int* __restrict__ deg,
    const int* __restrict__ eidx, const float* __restrict__ b1,
    unsigned short* __restrict__ hpb) {
  int wid = (int)((blockIdx.x * blockDim.x + threadIdx.x) >> 6);
  int lane = threadIdx.x & 63;
  if (wid >= N_NODES) return;
  int c = lane & 31, half = lane >> 5;
  int off = offs[wid];
  int dg = deg[wid];
  float acc = 0.f;
  int k = half;
  for (; k + 14 < dg; k += 16) {
    int s0 = eidx[off + k];
    int s1 = eidx[off + k + 2];
    int s2 = eidx[off + k + 4];
    int s3 = eidx[off + k + 6];
    int s4 = eidx[off + k + 8];
    int s5 = eidx[off + k + 10];
    int s6 = eidx[off + k + 12];
    int s7 = eidx[off + k + 14];
    float a0 = bf2f(xlb[s0 * 32 + c]);
    float a1 = bf2f(xlb[s1 * 32 + c]);
    float a2 = bf2f(xlb[s2 * 32 + c]);
    float a3 = bf2f(xlb[s3 * 32 + c]);
    float a4 = bf2f(xlb[s4 * 32 + c]);
    float a5 = bf2f(xlb[s5 * 32 + c]);
    float a6 = bf2f(xlb[s6 * 32 + c]);
    float a7 = bf2f(xlb[s7 * 32 + c]);
    acc += a0; acc += a1; acc += a2; acc += a3;
    acc += a4; acc += a5; acc += a6; acc += a7;
  }
  for (; k + 2 < dg; k += 4) {
    int s0 = eidx[off + k];
    int s1 = eidx[off + k + 2];
    float a0 = bf2f(xlb[s0 * 32 + c]);
    float a1 = bf2f(xlb[s1 * 32 + c]);
    acc += a0; acc += a1;
  }
  for (; k < dg; k += 2) {
    int s = eidx[off + k];
    acc += bf2f(xlb[s * 32 + c]);
  }
  acc += __shfl_xor(acc, 32, 64);
  if (lane < 32) {
    float inv = 1.0f / fmaxf((float)dg, 1.0f);
    int j = wid * 32 + c;
    float v = acc * inv + b1[c] + xr[j];
    v = (v > 0.f) ? v : 0.01f * v;
    float h = keep_bit(DK0.a, DK0.b, (unsigned)j) ? 2.0f * v : 0.0f;
    hpb[j] = f2bf(h);
  }
}

// ---- Gather layer 2 fused with output GEMM + dropout + L2 norm ----------
__global__ __launch_bounds__(256) void k_out(
    const unsigned short* __restrict__ hpb, const int* __restrict__ offs,
    const int* __restrict__ deg, const int* __restrict__ eidx,
    const float* __restrict__ W2l, const float* __restrict__ b2,
    const float* __restrict__ W2r, float* __restrict__ out) {
  int wid = (int)((blockIdx.x * blockDim.x + threadIdx.x) >> 6);
  int lane = threadIdx.x & 63;
  if (wid >= N_NODES) return;
  int c = lane & 31, half = lane >> 5;
  int off = offs[wid];
  int dg = deg[wid];
  float acc = 0.f;
  int k = half;
  for (; k + 14 < dg; k += 16) {
    int s0 = eidx[off + k];
    int s1 = eidx[off + k + 2];
    int s2 = eidx[off + k + 4];
    int s3 = eidx[off + k + 6];
    int s4 = eidx[off + k + 8];
    int s5 = eidx[off + k + 10];
    int s6 = eidx[off + k + 12];
    int s7 = eidx[off + k + 14];
    float a0 = bf2f(hpb[s0 * 32 + c]);
    float a1 = bf2f(hpb[s1 * 32 + c]);
    float a2 = bf2f(hpb[s2 * 32 + c]);
    float a3 = bf2f(hpb[s3 * 32 + c]);
    float a4 = bf2f(hpb[s4 * 32 + c]);
    float a5 = bf2f(hpb[s5 * 32 + c]);
    float a6 = bf2f(hpb[s6 * 32 + c]);
    float a7 = bf2f(hpb[s7 * 32 + c]);
    acc += a0; acc += a1; acc += a2; acc += a3;
    acc += a4; acc += a5; acc += a6; acc += a7;
  }
  for (; k + 2 < dg; k += 4) {
    int s0 = eidx[off + k];
    int s1 = eidx[off + k + 2];
    float a0 = bf2f(hpb[s0 * 32 + c]);
    float a1 = bf2f(hpb[s1 * 32 + c]);
    acc += a0; acc += a1;
  }
  for (; k < dg; k += 2) {
    int s = eidx[off + k];
    acc += bf2f(hpb[s * 32 + c]);
  }
  acc += __shfl_xor(acc, 32, 64);
  float inv = 1.0f / fmaxf((float)dg, 1.0f);
  // lanes 0..31: aggregated mean row; lanes 32..63: node's own hp row
  float rv = (lane < 32) ? acc * inv : bf2f(hpb[wid * 32 + c]);
  float s1 = 0.f, s2 = 0.f;
#pragma unroll
  for (int kk = 0; kk < 32; ++kk) {
    float a = __shfl(rv, kk, 64);
    float h = __shfl(rv, 32 + kk, 64);
    s1 += a * W2l[kk * 64 + lane];
    s2 += h * W2r[kk * 64 + lane];
  }
  float v = s1 + b2[lane] + s2;
  unsigned j = (unsigned)(wid * 64 + lane);
  float d = keep_bit(DK1.a, DK1.b, j) ? 2.0f * v : 0.0f;
  float ss = d * d;
#pragma unroll
  for (int o = 32; o > 0; o >>= 1) ss += __shfl_xor(ss, o, 64);
  float scale = 1.0f / fmaxf(sqrtf(ss), 1e-12f);
  out[j] = d * scale;
}

// --------------------------------------------------------------------------
extern "C" void kernel_launch(void* const* d_in, const int* in_sizes, int n_in,
                              void* d_out, int out_size, void* d_ws, size_t ws_size,
                              hipStream_t stream) {
  const float* x   = (const float*)d_in[0];
  const int*   ei  = (const int*)d_in[1];
  const float* W1l = (const float*)d_in[2];
  const float* b1  = (const float*)d_in[3];
  const float* W1r = (const float*)d_in[4];
  const float* W2l = (const float*)d_in[5];
  const float* b2  = (const float*)d_in[6];
  const float* W2r = (const float*)d_in[7];
  float* out = (float*)d_out;

  const int* src = ei;            // edge_index[0]
  const int* dst = ei + N_EDGES;  // edge_index[1]

  const size_t F32 = (size_t)N_NODES * 32;
  unsigned short* xlb = (unsigned short*)d_ws;       // 6.4 MB (bf16)
  unsigned short* hpb = xlb + F32;                   // 6.4 MB (bf16)
  float* xr     = (float*)(hpb + F32);               // 12.8 MB
  int* scur     = (int*)(xr + F32);                  // 100 KB
  int* bbase    = scur + NB * SEG;                   // 12.5 KB
  int* deg      = bbase + NB;                        // 400 KB
  int* offs     = deg + N_NODES;                     // 400 KB
  int* eidx     = offs + N_NODES;                    // 6.4 MB
  unsigned* buf = (unsigned*)(eidx + N_EDGES);       // 12.8 MB

  hipMemsetAsync(scur, 0, (size_t)NB * SEG * sizeof(int), stream);

  const int EB = (N_EDGES + 255) / 256;
  k_bin<<<EB, 256, 0, stream>>>(src, dst, scur, buf);
  k_bscan<<<1, 1024, 0, stream>>>(scur, bbase);
  k_bfill<<<NB, 256, 0, stream>>>(buf, scur, bbase, deg, offs, eidx);

  k_transform1<<<(N_NODES + 3) / 4, 256, 0, stream>>>(x, W1l, W1r, xlb, xr);
  k_gather1<<<(N_NODES + 3) / 4, 256, 0, stream>>>(xlb, xr, offs, deg, eidx, b1, hpb);
  k_out<<<(N_NODES + 3) / 4, 256, 0, stream>>>(hpb, offs, deg, eidx, W2l, b2, W2r, out);
}

// Round 8
// 397.027 us; speedup vs baseline: 1.0010x; 1.0010x over previous
//
#include <hip/hip_runtime.h>

#define N_NODES 100000
#define N_EDGES 1600000
#define NPB 32                       // nodes per bucket (dst >> 5)
#define NB (N_NODES / NPB)           // 3125 buckets
#define SEG 8                        // segments per bucket (XCD-local append)
#define CAP_S 128                    // slots per segment (mean 64 + 8 sigma)

// ---------------- JAX threefry2x32 (partitionable scheme) ----------------
struct U2 { unsigned a, b; };

__host__ __device__ constexpr U2 tf2x32(unsigned k0, unsigned k1, unsigned c0, unsigned c1) {
  unsigned ks2 = k0 ^ k1 ^ 0x1BD11BDAu;
  unsigned x0 = c0 + k0, x1 = c1 + k1;
#define TFR(r) { x0 += x1; x1 = (x1 << (r)) | (x1 >> (32 - (r))); x1 ^= x0; }
  TFR(13) TFR(15) TFR(26) TFR(6)
  x0 += k1;  x1 += ks2 + 1u;
  TFR(17) TFR(29) TFR(16) TFR(24)
  x0 += ks2; x1 += k0 + 2u;
  TFR(13) TFR(15) TFR(26) TFR(6)
  x0 += k0;  x1 += k1 + 3u;
  TFR(17) TFR(29) TFR(16) TFR(24)
  x0 += k1;  x1 += ks2 + 4u;
  TFR(13) TFR(15) TFR(26) TFR(6)
  x0 += ks2; x1 += k0 + 5u;
#undef TFR
  return U2{x0, x1};
}

constexpr U2 DK0 = tf2x32(0u, 42u, 0u, 0u);
constexpr U2 DK1 = tf2x32(0u, 42u, 0u, 1u);

__device__ __forceinline__ bool keep_bit(unsigned k0, unsigned k1, unsigned j) {
  U2 w = tf2x32(k0, k1, 0u, j);
  return ((w.a ^ w.b) >> 31) == 0u;
}

// bf16 storage helpers (RNE pack, shift unpack)
__device__ __forceinline__ unsigned short f2bf(float f) {
  unsigned u = __float_as_uint(f);
  u += 0x7FFFu + ((u >> 16) & 1u);
  return (unsigned short)(u >> 16);
}
__device__ __forceinline__ float bf2f(unsigned short s) {
  return __uint_as_float((unsigned)s << 16);
}

// ------ Kernel A: xl = bf16(x@W1_l), xr = x@W1_r (wave per row) ----------
__global__ __launch_bounds__(256) void k_transform1(
    const float* __restrict__ x, const float* __restrict__ Wl,
    const float* __restrict__ Wr, unsigned short* __restrict__ xlb,
    float* __restrict__ xr) {
  int wid = (int)((blockIdx.x * blockDim.x + threadIdx.x) >> 6);
  int lane = threadIdx.x & 63;
  if (wid >= N_NODES) return;
  float xv = x[wid * 64 + lane];
  const float* W = (lane < 32) ? Wl : Wr;
  int c = lane & 31;
  float s = 0.f;
#pragma unroll
  for (int k = 0; k < 64; ++k) {
    float b = __shfl(xv, k, 64);
    s += b * W[k * 32 + c];
  }
  if (lane < 32) xlb[wid * 32 + c] = f2bf(s);
  else           xr[wid * 32 + c] = s;
}

// ---------------- Binning: 8 XCD-local segments per bucket ---------------
__global__ __launch_bounds__(256) void k_bin(
    const int* __restrict__ src, const int* __restrict__ dst,
    int* __restrict__ scur, unsigned* __restrict__ buf) {
  int e = (int)(blockIdx.x * blockDim.x + threadIdx.x);
  if (e >= N_EDGES) return;
  int d = dst[e];
  int cell = (d >> 5) * SEG + (blockIdx.x & (SEG - 1));
  unsigned packed = (unsigned)src[e] | ((unsigned)(d & 31) << 17);
  int p = atomicAdd(&scur[cell], 1);
  if (p < CAP_S) buf[(size_t)cell * CAP_S + p] = packed;
}

// --------- single-block exclusive scan of bucket totals -> bbase ----------
__global__ __launch_bounds__(1024) void k_bscan(
    const int* __restrict__ scur, int* __restrict__ bbase) {
  __shared__ int warp_sums[16];
  __shared__ int s_running;
  int t = threadIdx.x;
  int lane = t & 63, w = t >> 6;
  if (t == 0) s_running = 0;
  __syncthreads();
  for (int base = 0; base < NB; base += 1024) {
    int i = base + t;
    int v = 0;
    if (i < NB) {
#pragma unroll
      for (int g = 0; g < SEG; ++g) v += min(scur[i * SEG + g], CAP_S);
    }
    int x = v;
#pragma unroll
    for (int o = 1; o < 64; o <<= 1) {
      int y = __shfl_up(x, o, 64);
      if (lane >= o) x += y;
    }
    if (lane == 63) warp_sums[w] = x;
    __syncthreads();
    if (w == 0) {
      int ws = (lane < 16) ? warp_sums[lane] : 0;
#pragma unroll
      for (int o = 1; o < 16; o <<= 1) {
        int y = __shfl_up(ws, o, 64);
        if (lane >= o) ws += y;
      }
      if (lane < 16) warp_sums[lane] = ws;
    }
    __syncthreads();
    int incl = x + (w > 0 ? warp_sums[w - 1] : 0);
    int excl = s_running + incl - v;
    if (i < NB) bbase[i] = excl;
    __syncthreads();
    if (t == 1023) s_running += incl;
    __syncthreads();
  }
}

// ------ block per bucket: LDS degree count + prefix, coalesced CSR fill ---
__global__ __launch_bounds__(256) void k_bfill(
    const unsigned* __restrict__ buf, const int* __restrict__ scur,
    const int* __restrict__ bbase, int* __restrict__ deg,
    int* __restrict__ offs, int* __restrict__ eidx) {
  __shared__ int ncnt[NPB];
  __shared__ int ncur[NPB];
  __shared__ int segn[SEG];
  int b = blockIdx.x, t = threadIdx.x;
  if (t < NPB) ncnt[t] = 0;
  if (t < SEG) segn[t] = min(scur[b * SEG + t], CAP_S);
  __syncthreads();
  const unsigned* bb = buf + (size_t)b * SEG * CAP_S;
  for (int slot = t; slot < SEG * CAP_S; slot += 256) {
    int g = slot / CAP_S, j = slot % CAP_S;
    if (j < segn[g]) atomicAdd(&ncnt[bb[slot] >> 17], 1);
  }
  __syncthreads();
  if (t < 64) {                       // wave 0: 32-wide exclusive scan
    int lane = t;
    int c = (lane < NPB) ? ncnt[lane] : 0;
    int x = c;
#pragma unroll
    for (int o = 1; o < 32; o <<= 1) {
      int y = __shfl_up(x, o, 64);
      if (lane >= o) x += y;
    }
    if (lane < NPB) {
      int excl = x - c;
      ncur[lane] = excl;
      int gn = b * NPB + lane;
      deg[gn] = c;
      offs[gn] = bbase[b] + excl;
    }
  }
  __syncthreads();
  int base = bbase[b];
  for (int slot = t; slot < SEG * CAP_S; slot += 256) {
    int g = slot / CAP_S, j = slot % CAP_S;
    if (j < segn[g]) {
      unsigned w = bb[slot];
      int p = atomicAdd(&ncur[w >> 17], 1);
      eidx[base + p] = (int)(w & 0x1FFFF);
    }
  }
}

// ---- Gather layer 1: hp = bf16(dropout(lrelu(mean(xl[nbrs])+b1+xr))) ----
// One wave per node. Lane L: edge-slot g=L>>3, 8B chunk ch=L&7, so one
// uint2 load fetches 8 different 64B rows. Indices come from one 32B
// contiguous load. Group-reduce + redistribute after reconvergence.
__global__ __launch_bounds__(256) void k_gather1(
    const unsigned short* __restrict__ xlb, const float* __restrict__ xr,
    const int* __restrict__ offs, const int* __restrict__ deg,
    const int* __restrict__ eidx, const float* __restrict__ b1,
    unsigned short* __restrict__ hpb) {
  int wid = (int)((blockIdx.x * blockDim.x + threadIdx.x) >> 6);
  int lane = threadIdx.x & 63;
  if (wid >= N_NODES) return;
  int g = lane >> 3, ch = lane & 7;
  int off = offs[wid];
  int dg = deg[wid];
  const uint2* x2 = (const uint2*)xlb;
  float a0 = 0.f, a1 = 0.f, a2 = 0.f, a3 = 0.f;
  int k = 0;
  for (; k + 16 <= dg; k += 16) {
    int s0 = eidx[off + k + g];
    int s1 = eidx[off + k + 8 + g];
    uint2 r0 = x2[s0 * 8 + ch];
    uint2 r1 = x2[s1 * 8 + ch];
    a0 += __uint_as_float(r0.x << 16);
    a1 += __uint_as_float(r0.x & 0xFFFF0000u);
    a2 += __uint_as_float(r0.y << 16);
    a3 += __uint_as_float(r0.y & 0xFFFF0000u);
    a0 += __uint_as_float(r1.x << 16);
    a1 += __uint_as_float(r1.x & 0xFFFF0000u);
    a2 += __uint_as_float(r1.y << 16);
    a3 += __uint_as_float(r1.y & 0xFFFF0000u);
  }
  for (; k < dg; k += 8) {
    if (k + g < dg) {
      int s = eidx[off + k + g];
      uint2 r = x2[s * 8 + ch];
      a0 += __uint_as_float(r.x << 16);
      a1 += __uint_as_float(r.x & 0xFFFF0000u);
      a2 += __uint_as_float(r.y << 16);
      a3 += __uint_as_float(r.y & 0xFFFF0000u);
    }
  }
  // reduce across the 8 edge-groups (lane bits 3..5)
  a0 += __shfl_xor(a0, 8, 64); a0 += __shfl_xor(a0, 16, 64); a0 += __shfl_xor(a0, 32, 64);
  a1 += __shfl_xor(a1, 8, 64); a1 += __shfl_xor(a1, 16, 64); a1 += __shfl_xor(a1, 32, 64);
  a2 += __shfl_xor(a2, 8, 64); a2 += __shfl_xor(a2, 16, 64); a2 += __shfl_xor(a2, 32, 64);
  a3 += __shfl_xor(a3, 8, 64); a3 += __shfl_xor(a3, 16, 64); a3 += __shfl_xor(a3, 32, 64);
  // redistribute: lane L (<32) takes column L = chunk*4 + sub
  int chunk = lane >> 2, sub = lane & 3;
  float t0 = __shfl(a0, chunk, 64);
  float t1 = __shfl(a1, chunk, 64);
  float t2 = __shfl(a2, chunk, 64);
  float t3 = __shfl(a3, chunk, 64);
  float val = (sub == 0) ? t0 : (sub == 1) ? t1 : (sub == 2) ? t2 : t3;
  if (lane < 32) {
    float inv = 1.0f / fmaxf((float)dg, 1.0f);
    int j = wid * 32 + lane;
    float v = val * inv + b1[lane] + xr[j];
    v = (v > 0.f) ? v : 0.01f * v;
    float h = keep_bit(DK0.a, DK0.b, (unsigned)j) ? 2.0f * v : 0.0f;
    hpb[j] = f2bf(h);
  }
}

// ---- Gather layer 2 fused with output GEMM + dropout + L2 norm ----------
__global__ __launch_bounds__(256) void k_out(
    const unsigned short* __restrict__ hpb, const int* __restrict__ offs,
    const int* __restrict__ deg, const int* __restrict__ eidx,
    const float* __restrict__ W2l, const float* __restrict__ b2,
    const float* __restrict__ W2r, float* __restrict__ out) {
  int wid = (int)((blockIdx.x * blockDim.x + threadIdx.x) >> 6);
  int lane = threadIdx.x & 63;
  if (wid >= N_NODES) return;
  int g = lane >> 3, ch = lane & 7;
  int off = offs[wid];
  int dg = deg[wid];
  const uint2* h2 = (const uint2*)hpb;
  float a0 = 0.f, a1 = 0.f, a2 = 0.f, a3 = 0.f;
  int k = 0;
  for (; k + 16 <= dg; k += 16) {
    int s0 = eidx[off + k + g];
    int s1 = eidx[off + k + 8 + g];
    uint2 r0 = h2[s0 * 8 + ch];
    uint2 r1 = h2[s1 * 8 + ch];
    a0 += __uint_as_float(r0.x << 16);
    a1 += __uint_as_float(r0.x & 0xFFFF0000u);
    a2 += __uint_as_float(r0.y << 16);
    a3 += __uint_as_float(r0.y & 0xFFFF0000u);
    a0 += __uint_as_float(r1.x << 16);
    a1 += __uint_as_float(r1.x & 0xFFFF0000u);
    a2 += __uint_as_float(r1.y << 16);
    a3 += __uint_as_float(r1.y & 0xFFFF0000u);
  }
  for (; k < dg; k += 8) {
    if (k + g < dg) {
      int s = eidx[off + k + g];
      uint2 r = h2[s * 8 + ch];
      a0 += __uint_as_float(r.x << 16);
      a1 += __uint_as_float(r.x & 0xFFFF0000u);
      a2 += __uint_as_float(r.y << 16);
      a3 += __uint_as_float(r.y & 0xFFFF0000u);
    }
  }
  a0 += __shfl_xor(a0, 8, 64); a0 += __shfl_xor(a0, 16, 64); a0 += __shfl_xor(a0, 32, 64);
  a1 += __shfl_xor(a1, 8, 64); a1 += __shfl_xor(a1, 16, 64); a1 += __shfl_xor(a1, 32, 64);
  a2 += __shfl_xor(a2, 8, 64); a2 += __shfl_xor(a2, 16, 64); a2 += __shfl_xor(a2, 32, 64);
  a3 += __shfl_xor(a3, 8, 64); a3 += __shfl_xor(a3, 16, 64); a3 += __shfl_xor(a3, 32, 64);
  int chunk = lane >> 2, sub = lane & 3;
  float t0 = __shfl(a0, chunk, 64);
  float t1 = __shfl(a1, chunk, 64);
  float t2 = __shfl(a2, chunk, 64);
  float t3 = __shfl(a3, chunk, 64);
  float val = (sub == 0) ? t0 : (sub == 1) ? t1 : (sub == 2) ? t2 : t3;
  float inv = 1.0f / fmaxf((float)dg, 1.0f);
  // lanes 0..31: aggregated mean row; lanes 32..63: node's own hp row
  float rv = (lane < 32) ? val * inv : bf2f(hpb[wid * 32 + (lane - 32)]);
  float s1 = 0.f, s2 = 0.f;
#pragma unroll
  for (int kk = 0; kk < 32; ++kk) {
    float a = __shfl(rv, kk, 64);
    float h = __shfl(rv, 32 + kk, 64);
    s1 += a * W2l[kk * 64 + lane];
    s2 += h * W2r[kk * 64 + lane];
  }
  float v = s1 + b2[lane] + s2;
  unsigned j = (unsigned)(wid * 64 + lane);
  float d = keep_bit(DK1.a, DK1.b, j) ? 2.0f * v : 0.0f;
  float ss = d * d;
#pragma unroll
  for (int o = 32; o > 0; o >>= 1) ss += __shfl_xor(ss, o, 64);
  float scale = 1.0f / fmaxf(sqrtf(ss), 1e-12f);
  out[j] = d * scale;
}

// --------------------------------------------------------------------------
extern "C" void kernel_launch(void* const* d_in, const int* in_sizes, int n_in,
                              void* d_out, int out_size, void* d_ws, size_t ws_size,
                              hipStream_t stream) {
  const float* x   = (const float*)d_in[0];
  const int*   ei  = (const int*)d_in[1];
  const float* W1l = (const float*)d_in[2];
  const float* b1  = (const float*)d_in[3];
  const float* W1r = (const float*)d_in[4];
  const float* W2l = (const float*)d_in[5];
  const float* b2  = (const float*)d_in[6];
  const float* W2r = (const float*)d_in[7];
  float* out = (float*)d_out;

  const int* src = ei;            // edge_index[0]
  const int* dst = ei + N_EDGES;  // edge_index[1]

  const size_t F32 = (size_t)N_NODES * 32;
  unsigned short* xlb = (unsigned short*)d_ws;       // 6.4 MB (bf16)
  unsigned short* hpb = xlb + F32;                   // 6.4 MB (bf16)
  float* xr     = (float*)(hpb + F32);               // 12.8 MB
  int* scur     = (int*)(xr + F32);                  // 100 KB
  int* bbase    = scur + NB * SEG;                   // 12.5 KB
  int* deg      = bbase + NB;                        // 400 KB
  int* offs     = deg + N_NODES;                     // 400 KB
  int* eidx     = offs + N_NODES;                    // 6.4 MB
  unsigned* buf = (unsigned*)(eidx + N_EDGES);       // 12.8 MB

  hipMemsetAsync(scur, 0, (size_t)NB * SEG * sizeof(int), stream);

  const int EB = (N_EDGES + 255) / 256;
  k_bin<<<EB, 256, 0, stream>>>(src, dst, scur, buf);
  k_bscan<<<1, 1024, 0, stream>>>(scur, bbase);
  k_bfill<<<NB, 256, 0, stream>>>(buf, scur, bbase, deg, offs, eidx);

  k_transform1<<<(N_NODES + 3) / 4, 256, 0, stream>>>(x, W1l, W1r, xlb, xr);
  k_gather1<<<(N_NODES + 3) / 4, 256, 0, stream>>>(xlb, xr, offs, deg, eidx, b1, hpb);
  k_out<<<(N_NODES + 3) / 4, 256, 0, stream>>>(hpb, offs, deg, eidx, W2l, b2, W2r, out);
}

// Round 9
// 347.473 us; speedup vs baseline: 1.1438x; 1.1426x over previous
//
#include <hip/hip_runtime.h>

#define N_NODES 100000
#define N_EDGES 1600000
#define NPB 32                       // nodes per bucket (dst >> 5)
#define NB (N_NODES / NPB)           // 3125 buckets
#define CAP 704                      // slots per bucket (mean 512 + 8.5 sigma)
#define NCC 49                       // coarse cells (dst >> 11)
#define CAPA 34816                   // slots per coarse cell (mean 32768 + 11 sigma)
#define NFB 64                       // fine buckets per coarse cell
#define BPC 16                       // blocks per cell in pass B

// ---------------- JAX threefry2x32 (partitionable scheme) ----------------
struct U2 { unsigned a, b; };

__host__ __device__ constexpr U2 tf2x32(unsigned k0, unsigned k1, unsigned c0, unsigned c1) {
  unsigned ks2 = k0 ^ k1 ^ 0x1BD11BDAu;
  unsigned x0 = c0 + k0, x1 = c1 + k1;
#define TFR(r) { x0 += x1; x1 = (x1 << (r)) | (x1 >> (32 - (r))); x1 ^= x0; }
  TFR(13) TFR(15) TFR(26) TFR(6)
  x0 += k1;  x1 += ks2 + 1u;
  TFR(17) TFR(29) TFR(16) TFR(24)
  x0 += ks2; x1 += k0 + 2u;
  TFR(13) TFR(15) TFR(26) TFR(6)
  x0 += k0;  x1 += k1 + 3u;
  TFR(17) TFR(29) TFR(16) TFR(24)
  x0 += k1;  x1 += ks2 + 4u;
  TFR(13) TFR(15) TFR(26) TFR(6)
  x0 += ks2; x1 += k0 + 5u;
#undef TFR
  return U2{x0, x1};
}

constexpr U2 DK0 = tf2x32(0u, 42u, 0u, 0u);
constexpr U2 DK1 = tf2x32(0u, 42u, 0u, 1u);

__device__ __forceinline__ bool keep_bit(unsigned k0, unsigned k1, unsigned j) {
  U2 w = tf2x32(k0, k1, 0u, j);
  return ((w.a ^ w.b) >> 31) == 0u;
}

// bf16 storage helpers (RNE pack, shift unpack)
__device__ __forceinline__ unsigned short f2bf(float f) {
  unsigned u = __float_as_uint(f);
  u += 0x7FFFu + ((u >> 16) & 1u);
  return (unsigned short)(u >> 16);
}
__device__ __forceinline__ float bf2f(unsigned short s) {
  return __uint_as_float((unsigned)s << 16);
}

// ------ Kernel A: xl = bf16(x@W1_l), xr = x@W1_r (wave per row) ----------
__global__ __launch_bounds__(256) void k_transform1(
    const float* __restrict__ x, const float* __restrict__ Wl,
    const float* __restrict__ Wr, unsigned short* __restrict__ xlb,
    float* __restrict__ xr) {
  int wid = (int)((blockIdx.x * blockDim.x + threadIdx.x) >> 6);
  int lane = threadIdx.x & 63;
  if (wid >= N_NODES) return;
  float xv = x[wid * 64 + lane];
  const float* W = (lane < 32) ? Wl : Wr;
  int c = lane & 31;
  float s = 0.f;
#pragma unroll
  for (int k = 0; k < 64; ++k) {
    float b = __shfl(xv, k, 64);
    s += b * W[k * 32 + c];
  }
  if (lane < 32) xlb[wid * 32 + c] = f2bf(s);
  else           xr[wid * 32 + c] = s;
}

// ------ Pass A: LDS-staged partition by coarse cell (dst>>11), 49 cells ---
// Staged reorder + coalesced copy-out -> stores are contiguous runs
// (~42 entries avg) = full sectors, killing the 9x write amplification.
__global__ __launch_bounds__(256) void k_binA(
    const int* __restrict__ src, const int* __restrict__ dst,
    int* __restrict__ curA, unsigned* __restrict__ bufA) {
  __shared__ int hist[NCC];
  __shared__ int offsL[NCC + 1];
  __shared__ int baseL[NCC];
  __shared__ int place[NCC];
  __shared__ unsigned stag[2048];
  int t = threadIdx.x;
  for (long long start = (long long)blockIdx.x * 2048; start < N_EDGES;
       start += (long long)gridDim.x * 2048) {
    int n = (int)min((long long)2048, (long long)N_EDGES - start);
    for (int i = t; i < NCC; i += 256) hist[i] = 0;
    __syncthreads();
    unsigned pv[8]; int pc[8];
#pragma unroll
    for (int i = 0; i < 8; ++i) {
      int idx = t + i * 256;
      if (idx < n) {
        int d = dst[start + idx];
        int s = src[start + idx];
        int cc = d >> 11;
        pc[i] = cc;
        pv[i] = (unsigned)s | ((unsigned)(d & 2047) << 17);
        atomicAdd(&hist[cc], 1);
      } else pc[i] = -1;
    }
    __syncthreads();
    if (t < 64) {                      // wave 0: 64-lane inclusive scan
      int lane = t;
      int v = (lane < NCC) ? hist[lane] : 0;
      int x = v;
#pragma unroll
      for (int o = 1; o < 64; o <<= 1) {
        int y = __shfl_up(x, o, 64);
        if (lane >= o) x += y;
      }
      if (lane < NCC) {
        offsL[lane] = x - v;
        place[lane] = 0;
        if (v > 0) baseL[lane] = atomicAdd(&curA[lane], v);
      }
      if (lane == NCC - 1) offsL[NCC] = x;
    }
    __syncthreads();
#pragma unroll
    for (int i = 0; i < 8; ++i) {
      if (pc[i] >= 0) {
        int p = atomicAdd(&place[pc[i]], 1);
        stag[offsL[pc[i]] + p] = pv[i];
      }
    }
    __syncthreads();
    for (int s2 = t; s2 < n; s2 += 256) {   // coalesced copy-out
      int lo = 0, hi = NCC;
      while (hi - lo > 1) { int mid = (lo + hi) >> 1; if (offsL[mid] <= s2) lo = mid; else hi = mid; }
      int pos = baseL[lo] + (s2 - offsL[lo]);
      if (pos < CAPA) bufA[(size_t)lo * CAPA + pos] = stag[s2];
    }
    __syncthreads();
  }
}

// ------ Pass B: refine each coarse cell into 64 fine buckets -------------
__global__ __launch_bounds__(256) void k_binB(
    const unsigned* __restrict__ bufA, const int* __restrict__ curA,
    int* __restrict__ cur, unsigned* __restrict__ buf) {
  __shared__ int hist[NFB];
  __shared__ int offsL[NFB + 1];
  __shared__ int baseL[NFB];
  __shared__ int place[NFB];
  __shared__ unsigned stag[2048];
  int cellc = blockIdx.x / BPC;
  int slice = blockIdx.x % BPC;
  int t = threadIdx.x;
  int cnt = min(curA[cellc], CAPA);
  const unsigned* in = bufA + (size_t)cellc * CAPA;
  for (int start = slice * 2048; start < cnt; start += BPC * 2048) {
    int n = min(2048, cnt - start);
    for (int i = t; i < NFB; i += 256) hist[i] = 0;
    __syncthreads();
    unsigned pv[8]; int pb[8];
#pragma unroll
    for (int i = 0; i < 8; ++i) {
      int idx = t + i * 256;
      if (idx < n) {
        unsigned w = in[start + idx];
        int dlow = (int)(w >> 17);           // 11 bits
        int fb = dlow >> 5;                  // 0..63
        pb[i] = fb;
        pv[i] = (w & 0x1FFFFu) | ((unsigned)(dlow & 31) << 17);
        atomicAdd(&hist[fb], 1);
      } else pb[i] = -1;
    }
    __syncthreads();
    if (t < 64) {
      int lane = t;
      int v = hist[lane];
      int x = v;
#pragma unroll
      for (int o = 1; o < 64; o <<= 1) {
        int y = __shfl_up(x, o, 64);
        if (lane >= o) x += y;
      }
      offsL[lane] = x - v;
      place[lane] = 0;
      if (v > 0) baseL[lane] = atomicAdd(&cur[cellc * NFB + lane], v);
      if (lane == 63) offsL[NFB] = x;
    }
    __syncthreads();
#pragma unroll
    for (int i = 0; i < 8; ++i) {
      if (pb[i] >= 0) {
        int p = atomicAdd(&place[pb[i]], 1);
        stag[offsL[pb[i]] + p] = pv[i];
      }
    }
    __syncthreads();
    for (int s2 = t; s2 < n; s2 += 256) {
      int lo = 0, hi = NFB;
      while (hi - lo > 1) { int mid = (lo + hi) >> 1; if (offsL[mid] <= s2) lo = mid; else hi = mid; }
      int pos = baseL[lo] + (s2 - offsL[lo]);
      if (pos < CAP) buf[(size_t)(cellc * NFB + lo) * CAP + pos] = stag[s2];
    }
    __syncthreads();
  }
}

// --------- single-block exclusive scan of bucket totals -> bbase ----------
__global__ __launch_bounds__(1024) void k_bscan(
    const int* __restrict__ cur, int* __restrict__ bbase) {
  __shared__ int warp_sums[16];
  __shared__ int s_running;
  int t = threadIdx.x;
  int lane = t & 63, w = t >> 6;
  if (t == 0) s_running = 0;
  __syncthreads();
  for (int base = 0; base < NB; base += 1024) {
    int i = base + t;
    int v = (i < NB) ? min(cur[i], CAP) : 0;
    int x = v;
#pragma unroll
    for (int o = 1; o < 64; o <<= 1) {
      int y = __shfl_up(x, o, 64);
      if (lane >= o) x += y;
    }
    if (lane == 63) warp_sums[w] = x;
    __syncthreads();
    if (w == 0) {
      int ws = (lane < 16) ? warp_sums[lane] : 0;
#pragma unroll
      for (int o = 1; o < 16; o <<= 1) {
        int y = __shfl_up(ws, o, 64);
        if (lane >= o) ws += y;
      }
      if (lane < 16) warp_sums[lane] = ws;
    }
    __syncthreads();
    int incl = x + (w > 0 ? warp_sums[w - 1] : 0);
    int excl = s_running + incl - v;
    if (i < NB) bbase[i] = excl;
    __syncthreads();
    if (t == 1023) s_running += incl;
    __syncthreads();
  }
}

// ------ block per bucket: LDS degree count + prefix, coalesced CSR fill ---
__global__ __launch_bounds__(256) void k_bfill(
    const unsigned* __restrict__ buf, const int* __restrict__ cur,
    const int* __restrict__ bbase, int* __restrict__ deg,
    int* __restrict__ offs, int* __restrict__ eidx) {
  __shared__ int ncnt[NPB];
  __shared__ int ncur[NPB];
  int b = blockIdx.x, t = threadIdx.x;
  if (t < NPB) ncnt[t] = 0;
  __syncthreads();
  int nb = min(cur[b], CAP);
  const unsigned* bb = buf + (size_t)b * CAP;
  for (int slot = t; slot < nb; slot += 256)
    atomicAdd(&ncnt[bb[slot] >> 17], 1);
  __syncthreads();
  if (t < 64) {                       // wave 0: 32-wide exclusive scan
    int lane = t;
    int c = (lane < NPB) ? ncnt[lane] : 0;
    int x = c;
#pragma unroll
    for (int o = 1; o < 32; o <<= 1) {
      int y = __shfl_up(x, o, 64);
      if (lane >= o) x += y;
    }
    if (lane < NPB) {
      int excl = x - c;
      ncur[lane] = excl;
      int gn = b * NPB + lane;
      deg[gn] = c;
      offs[gn] = bbase[b] + excl;
    }
  }
  __syncthreads();
  int base = bbase[b];
  for (int slot = t; slot < nb; slot += 256) {
    unsigned w = bb[slot];
    int p = atomicAdd(&ncur[w >> 17], 1);
    eidx[base + p] = (int)(w & 0x1FFFF);
  }
}

// ---- Gather layer 1: hp = bf16(dropout(lrelu(mean(xl[nbrs])+b1+xr))) ----
__global__ __launch_bounds__(256) void k_gather1(
    const unsigned short* __restrict__ xlb, const float* __restrict__ xr,
    const int* __restrict__ offs, const int* __restrict__ deg,
    const int* __restrict__ eidx, const float* __restrict__ b1,
    unsigned short* __restrict__ hpb) {
  int wid = (int)((blockIdx.x * blockDim.x + threadIdx.x) >> 6);
  int lane = threadIdx.x & 63;
  if (wid >= N_NODES) return;
  int g = lane >> 3, ch = lane & 7;
  int off = offs[wid];
  int dg = deg[wid];
  const uint2* x2 = (const uint2*)xlb;
  float a0 = 0.f, a1 = 0.f, a2 = 0.f, a3 = 0.f;
  int k = 0;
  for (; k + 16 <= dg; k += 16) {
    int s0 = eidx[off + k + g];
    int s1 = eidx[off + k + 8 + g];
    uint2 r0 = x2[s0 * 8 + ch];
    uint2 r1 = x2[s1 * 8 + ch];
    a0 += __uint_as_float(r0.x << 16);
    a1 += __uint_as_float(r0.x & 0xFFFF0000u);
    a2 += __uint_as_float(r0.y << 16);
    a3 += __uint_as_float(r0.y & 0xFFFF0000u);
    a0 += __uint_as_float(r1.x << 16);
    a1 += __uint_as_float(r1.x & 0xFFFF0000u);
    a2 += __uint_as_float(r1.y << 16);
    a3 += __uint_as_float(r1.y & 0xFFFF0000u);
  }
  for (; k < dg; k += 8) {
    if (k + g < dg) {
      int s = eidx[off + k + g];
      uint2 r = x2[s * 8 + ch];
      a0 += __uint_as_float(r.x << 16);
      a1 += __uint_as_float(r.x & 0xFFFF0000u);
      a2 += __uint_as_float(r.y << 16);
      a3 += __uint_as_float(r.y & 0xFFFF0000u);
    }
  }
  a0 += __shfl_xor(a0, 8, 64); a0 += __shfl_xor(a0, 16, 64); a0 += __shfl_xor(a0, 32, 64);
  a1 += __shfl_xor(a1, 8, 64); a1 += __shfl_xor(a1, 16, 64); a1 += __shfl_xor(a1, 32, 64);
  a2 += __shfl_xor(a2, 8, 64); a2 += __shfl_xor(a2, 16, 64); a2 += __shfl_xor(a2, 32, 64);
  a3 += __shfl_xor(a3, 8, 64); a3 += __shfl_xor(a3, 16, 64); a3 += __shfl_xor(a3, 32, 64);
  int chunk = lane >> 2, sub = lane & 3;
  float t0 = __shfl(a0, chunk, 64);
  float t1 = __shfl(a1, chunk, 64);
  float t2 = __shfl(a2, chunk, 64);
  float t3 = __shfl(a3, chunk, 64);
  float val = (sub == 0) ? t0 : (sub == 1) ? t1 : (sub == 2) ? t2 : t3;
  if (lane < 32) {
    float inv = 1.0f / fmaxf((float)dg, 1.0f);
    int j = wid * 32 + lane;
    float v = val * inv + b1[lane] + xr[j];
    v = (v > 0.f) ? v : 0.01f * v;
    float h = keep_bit(DK0.a, DK0.b, (unsigned)j) ? 2.0f * v : 0.0f;
    hpb[j] = f2bf(h);
  }
}

// ---- Gather layer 2 fused with output GEMM + dropout + L2 norm ----------
__global__ __launch_bounds__(256) void k_out(
    const unsigned short* __restrict__ hpb, const int* __restrict__ offs,
    const int* __restrict__ deg, const int* __restrict__ eidx,
    const float* __restrict__ W2l, const float* __restrict__ b2,
    const float* __restrict__ W2r, float* __restrict__ out) {
  int wid = (int)((blockIdx.x * blockDim.x + threadIdx.x) >> 6);
  int lane = threadIdx.x & 63;
  if (wid >= N_NODES) return;
  int g = lane >> 3, ch = lane & 7;
  int off = offs[wid];
  int dg = deg[wid];
  const uint2* h2 = (const uint2*)hpb;
  float a0 = 0.f, a1 = 0.f, a2 = 0.f, a3 = 0.f;
  int k = 0;
  for (; k + 16 <= dg; k += 16) {
    int s0 = eidx[off + k + g];
    int s1 = eidx[off + k + 8 + g];
    uint2 r0 = h2[s0 * 8 + ch];
    uint2 r1 = h2[s1 * 8 + ch];
    a0 += __uint_as_float(r0.x << 16);
    a1 += __uint_as_float(r0.x & 0xFFFF0000u);
    a2 += __uint_as_float(r0.y << 16);
    a3 += __uint_as_float(r0.y & 0xFFFF0000u);
    a0 += __uint_as_float(r1.x << 16);
    a1 += __uint_as_float(r1.x & 0xFFFF0000u);
    a2 += __uint_as_float(r1.y << 16);
    a3 += __uint_as_float(r1.y & 0xFFFF0000u);
  }
  for (; k < dg; k += 8) {
    if (k + g < dg) {
      int s = eidx[off + k + g];
      uint2 r = h2[s * 8 + ch];
      a0 += __uint_as_float(r.x << 16);
      a1 += __uint_as_float(r.x & 0xFFFF0000u);
      a2 += __uint_as_float(r.y << 16);
      a3 += __uint_as_float(r.y & 0xFFFF0000u);
    }
  }
  a0 += __shfl_xor(a0, 8, 64); a0 += __shfl_xor(a0, 16, 64); a0 += __shfl_xor(a0, 32, 64);
  a1 += __shfl_xor(a1, 8, 64); a1 += __shfl_xor(a1, 16, 64); a1 += __shfl_xor(a1, 32, 64);
  a2 += __shfl_xor(a2, 8, 64); a2 += __shfl_xor(a2, 16, 64); a2 += __shfl_xor(a2, 32, 64);
  a3 += __shfl_xor(a3, 8, 64); a3 += __shfl_xor(a3, 16, 64); a3 += __shfl_xor(a3, 32, 64);
  int chunk = lane >> 2, sub = lane & 3;
  float t0 = __shfl(a0, chunk, 64);
  float t1 = __shfl(a1, chunk, 64);
  float t2 = __shfl(a2, chunk, 64);
  float t3 = __shfl(a3, chunk, 64);
  float val = (sub == 0) ? t0 : (sub == 1) ? t1 : (sub == 2) ? t2 : t3;
  float inv = 1.0f / fmaxf((float)dg, 1.0f);
  float rv = (lane < 32) ? val * inv : bf2f(hpb[wid * 32 + (lane - 32)]);
  float s1 = 0.f, s2 = 0.f;
#pragma unroll
  for (int kk = 0; kk < 32; ++kk) {
    float a = __shfl(rv, kk, 64);
    float h = __shfl(rv, 32 + kk, 64);
    s1 += a * W2l[kk * 64 + lane];
    s2 += h * W2r[kk * 64 + lane];
  }
  float v = s1 + b2[lane] + s2;
  unsigned j = (unsigned)(wid * 64 + lane);
  float d = keep_bit(DK1.a, DK1.b, j) ? 2.0f * v : 0.0f;
  float ss = d * d;
#pragma unroll
  for (int o = 32; o > 0; o >>= 1) ss += __shfl_xor(ss, o, 64);
  float scale = 1.0f / fmaxf(sqrtf(ss), 1e-12f);
  out[j] = d * scale;
}

// --------------------------------------------------------------------------
extern "C" void kernel_launch(void* const* d_in, const int* in_sizes, int n_in,
                              void* d_out, int out_size, void* d_ws, size_t ws_size,
                              hipStream_t stream) {
  const float* x   = (const float*)d_in[0];
  const int*   ei  = (const int*)d_in[1];
  const float* W1l = (const float*)d_in[2];
  const float* b1  = (const float*)d_in[3];
  const float* W1r = (const float*)d_in[4];
  const float* W2l = (const float*)d_in[5];
  const float* b2  = (const float*)d_in[6];
  const float* W2r = (const float*)d_in[7];
  float* out = (float*)d_out;

  const int* src = ei;            // edge_index[0]
  const int* dst = ei + N_EDGES;  // edge_index[1]

  const size_t F32 = (size_t)N_NODES * 32;
  char* w = (char*)d_ws;
  // region 1 (12.8 MB): bufA (passes A/B) then xr (transform onward)
  unsigned* bufA = (unsigned*)w;                 // 49*34816*4 = 6.8 MB
  float* xr      = (float*)w;                    // 12.8 MB (bufA dead by then)
  w += F32 * sizeof(float);
  // region 2 (12.8 MB): buf (passes B/bfill) then xlb+hpb (transform onward)
  unsigned* buf  = (unsigned*)w;                 // 3125*704*4 = 8.8 MB
  unsigned short* xlb = (unsigned short*)w;      // 6.4 MB
  unsigned short* hpb = xlb + F32;               // 6.4 MB (buf dead by then)
  w += F32 * 2 * sizeof(unsigned short);
  int* curA  = (int*)w; w += NCC * sizeof(int);
  int* cur   = (int*)w; w += NB * sizeof(int);
  int* bbase = (int*)w; w += NB * sizeof(int);
  int* deg   = (int*)w; w += N_NODES * sizeof(int);
  int* offs  = (int*)w; w += N_NODES * sizeof(int);
  int* eidx  = (int*)w;                          // 6.4 MB

  hipMemsetAsync(curA, 0, (size_t)(NCC + NB) * sizeof(int), stream);

  k_binA<<<(N_EDGES + 2047) / 2048, 256, 0, stream>>>(src, dst, curA, bufA);
  k_binB<<<NCC * BPC, 256, 0, stream>>>(bufA, curA, cur, buf);
  k_bscan<<<1, 1024, 0, stream>>>(cur, bbase);
  k_bfill<<<NB, 256, 0, stream>>>(buf, cur, bbase, deg, offs, eidx);

  k_transform1<<<(N_NODES + 3) / 4, 256, 0, stream>>>(x, W1l, W1r, xlb, xr);
  k_gather1<<<(N_NODES + 3) / 4, 256, 0, stream>>>(xlb, xr, offs, deg, eidx, b1, hpb);
  k_out<<<(N_NODES + 3) / 4, 256, 0, stream>>>(hpb, offs, deg, eidx, W2l, b2, W2r, out);
}